// Round 9
// baseline (144.705 us; speedup 1.0000x reference)
//
#include <hip/hip_runtime.h>

#define NNODE 2048
#define DD    512
#define HHID  256
#define LLAT  16
#define H2    32   // 2L

typedef __attribute__((ext_vector_type(8))) short  short8;
typedef __attribute__((ext_vector_type(4))) float  f32x4;

__device__ __forceinline__ unsigned short f2bf(float x) {
    unsigned int u = __float_as_uint(x);
    unsigned int r = (u + 0x7fffu + ((u >> 16) & 1u)) >> 16;  // RNE
    return (unsigned short)r;
}
__device__ __forceinline__ float bf2f(unsigned short u) {
    return __uint_as_float(((unsigned int)u) << 16);
}

// ---------------- T0: convert A, X, W1 to bf16 (grid-stride over float4) ---------
__global__ __launch_bounds__(256) void t0_cvt(const float* __restrict__ A,
                                              const float* __restrict__ X,
                                              const float* __restrict__ W1,
                                              unsigned short* __restrict__ Abf,
                                              unsigned short* __restrict__ Xbf,
                                              unsigned short* __restrict__ W1bf) {
    const int NT = 1343488;   // 1048576 (A) + 262144 (X) + 32768 (W1) float4 units
    for (int v = blockIdx.x * 256 + threadIdx.x; v < NT; v += gridDim.x * 256) {
        const float* src; unsigned short* dst; int off;
        if (v < 1048576)      { src = A;  dst = Abf;  off = v; }
        else if (v < 1310720) { src = X;  dst = Xbf;  off = v - 1048576; }
        else                  { src = W1; dst = W1bf; off = v - 1310720; }
        float4 f = ((const float4*)src)[off];
        short4 h;
        h.x = (short)f2bf(f.x); h.y = (short)f2bf(f.y);
        h.z = (short)f2bf(f.z); h.w = (short)f2bf(f.w);
        ((short4*)dst)[off] = h;
    }
}

// ------- T1f: XWt = bf16(W1bf @ Xbf^T), FULL-K, 32x32 tiles, 512 blocks ----------
__global__ __launch_bounds__(256) void t1_full(const unsigned short* __restrict__ W1bf,
                                               const unsigned short* __restrict__ Xbf,
                                               unsigned short* __restrict__ XWt) {
    __shared__ __align__(16) unsigned short Ab[32][72];
    __shared__ __align__(16) unsigned short Bb[32][72];
    const int tid = threadIdx.x;
    const int n0 = blockIdx.x * 32;
    const int h0 = blockIdx.y * 32;
    const int lane = tid & 63, wave = tid >> 6;
    const int wm = wave >> 1, wn = wave & 1;
    const int lm = lane & 15, lk = (lane >> 4) * 8;
    const int sr = tid >> 3, sc = (tid & 7) * 8;   // 32 rows x 64 k, uint4/thread
    f32x4 acc = {};
    for (int it = 0; it < 8; ++it) {
        int kk = it * 64;
        *(uint4*)&Ab[sr][sc] = *(const uint4*)(W1bf + (size_t)(h0 + sr) * DD + kk + sc);
        *(uint4*)&Bb[sr][sc] = *(const uint4*)(Xbf  + (size_t)(n0 + sr) * DD + kk + sc);
        __syncthreads();
        #pragma unroll
        for (int ko = 0; ko < 2; ++ko) {
            short8 a = *(const short8*)&Ab[wm * 16 + lm][ko * 32 + lk];
            short8 b = *(const short8*)&Bb[wn * 16 + lm][ko * 32 + lk];
            acc = __builtin_amdgcn_mfma_f32_16x16x32_bf16(a, b, acc, 0, 0, 0);
        }
        __syncthreads();
    }
    #pragma unroll
    for (int r = 0; r < 4; ++r) {
        int row = h0 + wm * 16 + (lane >> 4) * 4 + r;
        int col = n0 + wn * 16 + lm;
        XWt[(size_t)row * NNODE + col] = f2bf(acc[r]);
    }
}

// ------- T2f: Hbf = bf16(leaky(A @ XW + b1)), FULL-K, 32x32 tiles, 512 blocks ----
// replaces t2_mfma(splitK=4)+t3h's Hp-reduce: kills the 33.6 MB Hp fp32 round-trip.
// Same grid/occupancy/LDS structure as the verified t1_full, plus reg-prefetch
// across the 32 K-iterations (K=2048, BK=64).
__global__ __launch_bounds__(256) void t2_full(const unsigned short* __restrict__ Abf,
                                               const unsigned short* __restrict__ XWt,
                                               const float* __restrict__ bias1,
                                               unsigned short* __restrict__ Hbf) {
    __shared__ __align__(16) unsigned short Ab[32][72];
    __shared__ __align__(16) unsigned short Bb[32][72];
    const int tid = threadIdx.x;
    const int m0 = blockIdx.x * 32;
    const int h0 = blockIdx.y * 32;
    const int lane = tid & 63, wave = tid >> 6;
    const int wm = wave >> 1, wn = wave & 1;
    const int lm = lane & 15, lk = (lane >> 4) * 8;
    const int sr = tid >> 3, sc = (tid & 7) * 8;   // 32 rows x 64 k, uint4/thread
    const unsigned short* aA = Abf + (size_t)(m0 + sr) * NNODE + sc;
    const unsigned short* aB = XWt + (size_t)(h0 + sr) * NNODE + sc;
    uint4 ra = *(const uint4*)aA;
    uint4 rb = *(const uint4*)aB;
    f32x4 acc = {};
    for (int it = 0; it < 32; ++it) {
        *(uint4*)&Ab[sr][sc] = ra;
        *(uint4*)&Bb[sr][sc] = rb;
        __syncthreads();
        if (it < 31) {
            ra = *(const uint4*)(aA + (it + 1) * 64);
            rb = *(const uint4*)(aB + (it + 1) * 64);
        }
        #pragma unroll
        for (int ko = 0; ko < 2; ++ko) {
            short8 a = *(const short8*)&Ab[wm * 16 + lm][ko * 32 + lk];
            short8 b = *(const short8*)&Bb[wn * 16 + lm][ko * 32 + lk];
            acc = __builtin_amdgcn_mfma_f32_16x16x32_bf16(a, b, acc, 0, 0, 0);
        }
        __syncthreads();
    }
    const int col = h0 + wn * 16 + lm;
    const float bb = bias1[col];
    #pragma unroll
    for (int r = 0; r < 4; ++r) {
        int row = m0 + wm * 16 + (lane >> 4) * 4 + r;
        float s = acc[r] + bb;
        s = fmaxf(s, 0.01f * s);
        Hbf[(size_t)row * HHID + col] = f2bf(s);
    }
}

// ---------------- T3: Gt[j][n] = bf16( sum_d Hbf[n][d] * Wcat[j][d] ) ------------
__global__ __launch_bounds__(256) void t3_g(const unsigned short* __restrict__ Hbf,
                                            const float* __restrict__ Wmu,
                                            const float* __restrict__ Wlv,
                                            unsigned short* __restrict__ Gt) {
    __shared__ float Hs[8][260];
    __shared__ float Ws[32][260];
    const int tid = threadIdx.x;
    const int n0 = blockIdx.x * 8;
    #pragma unroll
    for (int s = 0; s < 8; ++s) {
        int idx = tid + s * 256;            // float4 units, 0..2047
        int row = idx >> 6, c = (idx & 63) * 4;
        const float* src = (row < 16) ? (Wmu + (size_t)row * HHID)
                                      : (Wlv + (size_t)(row - 16) * HHID);
        *(float4*)&Ws[row][c] = *(const float4*)(src + c);
    }
    {
        int r = tid >> 5, seg = tid & 31;
        int d = seg * 8;
        ushort4 u0 = *(const ushort4*)(Hbf + (size_t)(n0 + r) * HHID + d);
        ushort4 u1 = *(const ushort4*)(Hbf + (size_t)(n0 + r) * HHID + d + 4);
        Hs[r][d + 0] = bf2f(u0.x); Hs[r][d + 1] = bf2f(u0.y);
        Hs[r][d + 2] = bf2f(u0.z); Hs[r][d + 3] = bf2f(u0.w);
        Hs[r][d + 4] = bf2f(u1.x); Hs[r][d + 5] = bf2f(u1.y);
        Hs[r][d + 6] = bf2f(u1.z); Hs[r][d + 7] = bf2f(u1.w);
    }
    __syncthreads();
    const int r = tid >> 5, j = tid & 31;
    float acc = 0.f;
    #pragma unroll 8
    for (int d4 = 0; d4 < 64; ++d4) {
        float4 a = *(const float4*)&Hs[r][d4 * 4];
        float4 b = *(const float4*)&Ws[j][d4 * 4];
        acc += a.x * b.x + a.y * b.y + a.z * b.z + a.w * b.w;
    }
    Gt[(size_t)j * NNODE + n0 + r] = f2bf(acc);
}

// ---------------- T4: Mp[s][m][c] = partial A @ G  (MFMA, splitK=8) --------------
__global__ __launch_bounds__(256) void t4_mfma(const unsigned short* __restrict__ Abf,
                                               const unsigned short* __restrict__ Gt,
                                               float* __restrict__ Mp) {
    __shared__ __align__(16) unsigned short Ab[64][40];
    __shared__ __align__(16) unsigned short Bb[32][40];
    const int tid = threadIdx.x;
    const int m0 = blockIdx.x * 64;
    const int ks = blockIdx.y;          // 0..7, K chunk of 256
    const int lane = tid & 63, wave = tid >> 6;
    const int lm = lane & 15, lk = (lane >> 4) * 8;
    const int sr = tid >> 2, sc = (tid & 3) * 8;
    f32x4 acc[2] = {};
    for (int it = 0; it < 8; ++it) {
        int kk = ks * 256 + it * 32;
        *(uint4*)&Ab[sr][sc] = *(const uint4*)(Abf + (size_t)(m0 + sr) * NNODE + kk + sc);
        if (tid < 128) {
            int row = tid >> 2, c = (tid & 3) * 8;
            *(uint4*)&Bb[row][c] = *(const uint4*)(Gt + (size_t)row * NNODE + kk + c);
        }
        __syncthreads();
        short8 a  = *(const short8*)&Ab[wave * 16 + lm][lk];
        short8 b0 = *(const short8*)&Bb[lm][lk];
        short8 b1 = *(const short8*)&Bb[16 + lm][lk];
        acc[0] = __builtin_amdgcn_mfma_f32_16x16x32_bf16(a, b0, acc[0], 0, 0, 0);
        acc[1] = __builtin_amdgcn_mfma_f32_16x16x32_bf16(a, b1, acc[1], 0, 0, 0);
        __syncthreads();
    }
    float* outp = Mp + (size_t)ks * 65536;
    #pragma unroll
    for (int ni = 0; ni < 2; ++ni)
        #pragma unroll
        for (int r = 0; r < 4; ++r) {
            int row = m0 + wave * 16 + (lane >> 4) * 4 + r;
            int col = ni * 16 + lm;
            outp[(size_t)row * H2 + col] = acc[ni][r];
        }
}

// ---------------- T5: reduce Mp; mu/logvar; Z; P', Q, and WP/WQ ------------------
__global__ __launch_bounds__(256) void t5_z(const float* __restrict__ Mp,
                                            const float* __restrict__ bmu,
                                            const float* __restrict__ blv,
                                            const float* __restrict__ eps,
                                            const float* __restrict__ Wd1,
                                            const float* __restrict__ bd1,
                                            const float* __restrict__ Wd2,
                                            float* __restrict__ out_mu,
                                            float* __restrict__ out_lv,
                                            float* __restrict__ Pp,
                                            float* __restrict__ Qq,
                                            float* __restrict__ WP,
                                            float* __restrict__ WQ) {
    __shared__ float Zs[16][16];
    __shared__ float Psh[16][32];
    __shared__ float Qsh[16][32];
    const int tid = threadIdx.x;
    const int n0 = blockIdx.x * 16;
    {
        int nl = tid >> 4, l = tid & 15;
        int n = n0 + nl;
        float m = bmu[l], lv = blv[l];
        #pragma unroll
        for (int s = 0; s < 8; ++s) {
            m  += Mp[(size_t)s * 65536 + (size_t)n * H2 + l];
            lv += Mp[(size_t)s * 65536 + (size_t)n * H2 + 16 + l];
        }
        out_mu[(size_t)n * LLAT + l] = m;
        out_lv[(size_t)n * LLAT + l] = lv;
        Zs[nl][l] = m + eps[(size_t)n * LLAT + l] * __expf(0.5f * lv);
    }
    __syncthreads();
    #pragma unroll
    for (int p = 0; p < 2; ++p) {
        int idx = tid + p * 256;            // 0..511
        int nl = idx >> 5, o = idx & 31;
        int n = n0 + nl;
        float ap = bd1[o], aq = 0.f;
        #pragma unroll
        for (int l = 0; l < 16; ++l) {
            float z = Zs[nl][l];
            ap = fmaf(z, Wd1[o * H2 + l],      ap);
            aq = fmaf(z, Wd1[o * H2 + 16 + l], aq);
        }
        Pp[(size_t)n * H2 + o] = ap;
        Qq[(size_t)n * H2 + o] = aq;
        Psh[nl][o] = ap;
        Qsh[nl][o] = aq;
    }
    __syncthreads();
    if (tid < 32) {
        int nl = tid & 15, sel = tid >> 4;
        float a = 0.f;
        if (sel == 0) {
            #pragma unroll
            for (int o = 0; o < 32; ++o) a = fmaf(Wd2[o], Psh[nl][o], a);
            WP[n0 + nl] = a;
        } else {
            #pragma unroll
            for (int o = 0; o < 32; ++o) a = fmaf(Wd2[o], Qsh[nl][o], a);
            WQ[n0 + nl] = a;
        }
    }
}

// ---------------- T6: decoder via leaky(x)=0.505x+0.495|x| decomposition ---------
__global__ __launch_bounds__(256) void t6_dec(const float* __restrict__ Pp,
                                              const float* __restrict__ Qq,
                                              const float* __restrict__ WP,
                                              const float* __restrict__ WQ,
                                              const float* __restrict__ Wd2,
                                              const float* __restrict__ bd2,
                                              float* __restrict__ Apred) {
    __shared__ float Qt[32][68];   // transposed Q tile, padded
    __shared__ float Ws2[32];
    __shared__ float WQs[64];
    const int tid = threadIdx.x;
    const int j0 = blockIdx.x * 64, i0 = blockIdx.y * 16;
    #pragma unroll
    for (int s = 0; s < 8; ++s) {
        int idx = tid + s * 256;            // 0..2047
        int j = idx >> 5, o = idx & 31;
        Qt[o][j] = Qq[(size_t)(j0 + j) * H2 + o];
    }
    if (tid < 32) Ws2[tid] = Wd2[tid];
    if (tid >= 64 && tid < 128) WQs[tid - 64] = WQ[j0 + tid - 64];
    const int i = i0 + (tid >> 4);
    const int jq = tid & 15;
    float p[32];
    const float4* P4 = (const float4*)(Pp + (size_t)i * H2);
    #pragma unroll
    for (int c = 0; c < 8; ++c) {
        float4 v = P4[c];
        p[c * 4] = v.x; p[c * 4 + 1] = v.y; p[c * 4 + 2] = v.z; p[c * 4 + 3] = v.w;
    }
    const float WPi = WP[i];
    __syncthreads();
    f32x4 acc = {0.f, 0.f, 0.f, 0.f};   // sum_o w*|P+Q|
    #pragma unroll
    for (int o = 0; o < 32; ++o) {
        float4 q = *(const float4*)&Qt[o][jq * 4];
        float w = Ws2[o], po = p[o];
        acc[0] = fmaf(w, fabsf(po + q.x), acc[0]);
        acc[1] = fmaf(w, fabsf(po + q.y), acc[1]);
        acc[2] = fmaf(w, fabsf(po + q.z), acc[2]);
        acc[3] = fmaf(w, fabsf(po + q.w), acc[3]);
    }
    float4 wq = *(const float4*)&WQs[jq * 4];
    const float base = fmaf(0.505f, WPi, bd2[0]);
    float4 r;
    float l0 = fmaf(0.505f, wq.x, fmaf(0.495f, acc[0], base));
    float l1 = fmaf(0.505f, wq.y, fmaf(0.495f, acc[1], base));
    float l2 = fmaf(0.505f, wq.z, fmaf(0.495f, acc[2], base));
    float l3 = fmaf(0.505f, wq.w, fmaf(0.495f, acc[3], base));
    r.x = 1.f / (1.f + __expf(-l0));
    r.y = 1.f / (1.f + __expf(-l1));
    r.z = 1.f / (1.f + __expf(-l2));
    r.w = 1.f / (1.f + __expf(-l3));
    *(float4*)(Apred + (size_t)i * NNODE + j0 + jq * 4) = r;
}

extern "C" void kernel_launch(void* const* d_in, const int* in_sizes, int n_in,
                              void* d_out, int out_size, void* d_ws, size_t ws_size,
                              hipStream_t stream) {
    const float* A   = (const float*)d_in[0];
    const float* X   = (const float*)d_in[1];
    const float* eps = (const float*)d_in[2];
    const float* W1  = (const float*)d_in[3];
    const float* b1  = (const float*)d_in[4];
    const float* Wmu = (const float*)d_in[5];
    const float* bmu = (const float*)d_in[6];
    const float* Wlv = (const float*)d_in[7];
    const float* blv = (const float*)d_in[8];
    const float* Wd1 = (const float*)d_in[9];
    const float* bd1 = (const float*)d_in[10];
    const float* Wd2 = (const float*)d_in[11];
    const float* bd2 = (const float*)d_in[12];
    float* out = (float*)d_out;
    char* ws = (char*)d_ws;

    // workspace carve (~15.6 MB), all buffers fully overwritten each call
    unsigned short* Abf  = (unsigned short*)(ws);               //  8,388,608
    unsigned short* Xbf  = (unsigned short*)(ws + 8388608);     //  2,097,152
    unsigned short* W1bf = (unsigned short*)(ws + 10485760);    //    262,144
    unsigned short* XWt  = (unsigned short*)(ws + 10747904);    //  1,048,576
    unsigned short* Hbf  = (unsigned short*)(ws + 11796480);    //  1,048,576
    unsigned short* Gt   = (unsigned short*)(ws + 12845056);    //    131,072
    float*          Mp   = (float*)(ws + 12976128);             //  2,097,152 (8 x 256KB)
    float*          Pp   = (float*)(ws + 15073280);             //    262,144
    float*          Qq   = (float*)(ws + 15335424);             //    262,144
    float*          WP   = (float*)(ws + 15597568);             //      8,192
    float*          WQ   = (float*)(ws + 15605760);             //      8,192

    float* out_mu = out + (size_t)NNODE * NNODE;
    float* out_lv = out_mu + NNODE * LLAT;

    t0_cvt <<<2048,            256, 0, stream>>>(A, X, W1, Abf, Xbf, W1bf);
    t1_full<<<dim3(64, 8),     256, 0, stream>>>(W1bf, Xbf, XWt);
    t2_full<<<dim3(64, 8),     256, 0, stream>>>(Abf, XWt, b1, Hbf);
    t3_g   <<<256,             256, 0, stream>>>(Hbf, Wmu, Wlv, Gt);
    t4_mfma<<<dim3(32, 8),     256, 0, stream>>>(Abf, Gt, Mp);
    t5_z   <<<128,             256, 0, stream>>>(Mp, bmu, blv, eps, Wd1, bd1, Wd2,
                                                 out_mu, out_lv, Pp, Qq, WP, WQ);
    t6_dec <<<dim3(32, 128),   256, 0, stream>>>(Pp, Qq, WP, WQ, Wd2, bd2, out);
}

// Round 10
// 136.431 us; speedup vs baseline: 1.0606x; 1.0606x over previous
//
#include <hip/hip_runtime.h>

#define NNODE 2048
#define DD    512
#define HHID  256
#define LLAT  16
#define H2    32   // 2L

typedef __attribute__((ext_vector_type(8))) short  short8;
typedef __attribute__((ext_vector_type(4))) float  f32x4;

__device__ __forceinline__ unsigned short f2bf(float x) {
    unsigned int u = __float_as_uint(x);
    unsigned int r = (u + 0x7fffu + ((u >> 16) & 1u)) >> 16;  // RNE
    return (unsigned short)r;
}
__device__ __forceinline__ float bf2f(unsigned short u) {
    return __uint_as_float(((unsigned int)u) << 16);
}

// ---------------- T0: convert A, X, W1 to bf16 (grid-stride over float4) ---------
__global__ __launch_bounds__(256) void t0_cvt(const float* __restrict__ A,
                                              const float* __restrict__ X,
                                              const float* __restrict__ W1,
                                              unsigned short* __restrict__ Abf,
                                              unsigned short* __restrict__ Xbf,
                                              unsigned short* __restrict__ W1bf) {
    const int NT = 1343488;   // 1048576 (A) + 262144 (X) + 32768 (W1) float4 units
    for (int v = blockIdx.x * 256 + threadIdx.x; v < NT; v += gridDim.x * 256) {
        const float* src; unsigned short* dst; int off;
        if (v < 1048576)      { src = A;  dst = Abf;  off = v; }
        else if (v < 1310720) { src = X;  dst = Xbf;  off = v - 1048576; }
        else                  { src = W1; dst = W1bf; off = v - 1310720; }
        float4 f = ((const float4*)src)[off];
        short4 h;
        h.x = (short)f2bf(f.x); h.y = (short)f2bf(f.y);
        h.z = (short)f2bf(f.z); h.w = (short)f2bf(f.w);
        ((short4*)dst)[off] = h;
    }
}

// ------- T1f: XWt = bf16(W1bf @ Xbf^T), FULL-K, 32x32 tiles, 512 blocks ----------
__global__ __launch_bounds__(256) void t1_full(const unsigned short* __restrict__ W1bf,
                                               const unsigned short* __restrict__ Xbf,
                                               unsigned short* __restrict__ XWt) {
    __shared__ __align__(16) unsigned short Ab[32][72];
    __shared__ __align__(16) unsigned short Bb[32][72];
    const int tid = threadIdx.x;
    const int n0 = blockIdx.x * 32;
    const int h0 = blockIdx.y * 32;
    const int lane = tid & 63, wave = tid >> 6;
    const int wm = wave >> 1, wn = wave & 1;
    const int lm = lane & 15, lk = (lane >> 4) * 8;
    const int sr = tid >> 3, sc = (tid & 7) * 8;   // 32 rows x 64 k, uint4/thread
    f32x4 acc = {};
    for (int it = 0; it < 8; ++it) {
        int kk = it * 64;
        *(uint4*)&Ab[sr][sc] = *(const uint4*)(W1bf + (size_t)(h0 + sr) * DD + kk + sc);
        *(uint4*)&Bb[sr][sc] = *(const uint4*)(Xbf  + (size_t)(n0 + sr) * DD + kk + sc);
        __syncthreads();
        #pragma unroll
        for (int ko = 0; ko < 2; ++ko) {
            short8 a = *(const short8*)&Ab[wm * 16 + lm][ko * 32 + lk];
            short8 b = *(const short8*)&Bb[wn * 16 + lm][ko * 32 + lk];
            acc = __builtin_amdgcn_mfma_f32_16x16x32_bf16(a, b, acc, 0, 0, 0);
        }
        __syncthreads();
    }
    #pragma unroll
    for (int r = 0; r < 4; ++r) {
        int row = h0 + wm * 16 + (lane >> 4) * 4 + r;
        int col = n0 + wn * 16 + lm;
        XWt[(size_t)row * NNODE + col] = f2bf(acc[r]);
    }
}

// ------ T2: Hp16[s][m][d] = bf16 partials of A @ XW  (MFMA, splitK=4) ------------
// R8 body; epilogue now stores bf16 partials (halves the Hp round-trip traffic).
__global__ __launch_bounds__(256) void t2_mfma(const unsigned short* __restrict__ Abf,
                                               const unsigned short* __restrict__ XWt,
                                               unsigned short* __restrict__ Hp16) {
    __shared__ __align__(16) unsigned short Ab[64][40];
    __shared__ __align__(16) unsigned short Bb[64][40];
    const int tid = threadIdx.x;
    const int m0 = blockIdx.x * 64;
    const int n0 = blockIdx.y * 64;
    const int ks = blockIdx.z;          // 0..3, K chunk of 512
    const int lane = tid & 63, wave = tid >> 6;
    const int wm = wave >> 1, wn = wave & 1;
    const int lm = lane & 15, lk = (lane >> 4) * 8;
    const int sr = tid >> 2, sc = (tid & 3) * 8;
    f32x4 acc[2][2] = {};
    for (int it = 0; it < 16; ++it) {
        int kk = ks * 512 + it * 32;
        *(uint4*)&Ab[sr][sc] = *(const uint4*)(Abf + (size_t)(m0 + sr) * NNODE + kk + sc);
        *(uint4*)&Bb[sr][sc] = *(const uint4*)(XWt + (size_t)(n0 + sr) * NNODE + kk + sc);
        __syncthreads();
        short8 a0 = *(const short8*)&Ab[wm * 32 + lm][lk];
        short8 a1 = *(const short8*)&Ab[wm * 32 + 16 + lm][lk];
        short8 b0 = *(const short8*)&Bb[wn * 32 + lm][lk];
        short8 b1 = *(const short8*)&Bb[wn * 32 + 16 + lm][lk];
        acc[0][0] = __builtin_amdgcn_mfma_f32_16x16x32_bf16(a0, b0, acc[0][0], 0, 0, 0);
        acc[0][1] = __builtin_amdgcn_mfma_f32_16x16x32_bf16(a0, b1, acc[0][1], 0, 0, 0);
        acc[1][0] = __builtin_amdgcn_mfma_f32_16x16x32_bf16(a1, b0, acc[1][0], 0, 0, 0);
        acc[1][1] = __builtin_amdgcn_mfma_f32_16x16x32_bf16(a1, b1, acc[1][1], 0, 0, 0);
        __syncthreads();
    }
    unsigned short* outp = Hp16 + (size_t)ks * 524288;
    #pragma unroll
    for (int mi = 0; mi < 2; ++mi)
        #pragma unroll
        for (int ni = 0; ni < 2; ++ni)
            #pragma unroll
            for (int r = 0; r < 4; ++r) {
                int row = m0 + wm * 32 + mi * 16 + (lane >> 4) * 4 + r;
                int col = n0 + wn * 32 + ni * 16 + lm;
                outp[(size_t)row * HHID + col] = f2bf(acc[mi][ni][r]);
            }
}

// ------- T3h: H row = leaky(sum_s bf16Hp[s] + b1) -> Gt = bf16(H @ Wcat^T) -------
__global__ __launch_bounds__(256) void t3h(const unsigned short* __restrict__ Hp16,
                                           const float* __restrict__ b1,
                                           const float* __restrict__ Wmu,
                                           const float* __restrict__ Wlv,
                                           unsigned short* __restrict__ Gt) {
    __shared__ float Hs[8][260];
    __shared__ float Ws[32][260];
    const int tid = threadIdx.x;
    const int n0 = blockIdx.x * 8;
    #pragma unroll
    for (int s = 0; s < 8; ++s) {
        int idx = tid + s * 256;            // float4 units, 0..2047
        int row = idx >> 6, c = (idx & 63) * 4;
        const float* src = (row < 16) ? (Wmu + (size_t)row * HHID)
                                      : (Wlv + (size_t)(row - 16) * HHID);
        *(float4*)&Ws[row][c] = *(const float4*)(src + c);
    }
    {   // fused t2r: sum 4 bf16 partial slices + bias, leaky, round to bf16.
        int r = tid >> 5, seg = tid & 31;
        int dcol = seg * 8;
        const unsigned short* base = Hp16 + (size_t)(n0 + r) * HHID + dcol;
        uint4 ua = *(const uint4*)(base);
        uint4 ub = *(const uint4*)(base + 524288);
        uint4 uc = *(const uint4*)(base + 1048576);
        uint4 ud = *(const uint4*)(base + 1572864);
        const unsigned short* pa = (const unsigned short*)&ua;
        const unsigned short* pb = (const unsigned short*)&ub;
        const unsigned short* pc = (const unsigned short*)&uc;
        const unsigned short* pd = (const unsigned short*)&ud;
        #pragma unroll
        for (int e = 0; e < 8; ++e) {
            float s = (bf2f(pa[e]) + bf2f(pb[e])) + (bf2f(pc[e]) + bf2f(pd[e]))
                      + b1[dcol + e];
            s = fmaxf(s, 0.01f * s);
            Hs[r][dcol + e] = bf2f(f2bf(s));
        }
    }
    __syncthreads();
    const int r = tid >> 5, j = tid & 31;
    float acc = 0.f;
    #pragma unroll 8
    for (int d4 = 0; d4 < 64; ++d4) {
        float4 a = *(const float4*)&Hs[r][d4 * 4];
        float4 b = *(const float4*)&Ws[j][d4 * 4];
        acc += a.x * b.x + a.y * b.y + a.z * b.z + a.w * b.w;
    }
    Gt[(size_t)j * NNODE + n0 + r] = f2bf(acc);
}

// ---------------- T4: Mp[s][m][c] = partial A @ G  (MFMA, splitK=8) --------------
__global__ __launch_bounds__(256) void t4_mfma(const unsigned short* __restrict__ Abf,
                                               const unsigned short* __restrict__ Gt,
                                               float* __restrict__ Mp) {
    __shared__ __align__(16) unsigned short Ab[64][40];
    __shared__ __align__(16) unsigned short Bb[32][40];
    const int tid = threadIdx.x;
    const int m0 = blockIdx.x * 64;
    const int ks = blockIdx.y;          // 0..7, K chunk of 256
    const int lane = tid & 63, wave = tid >> 6;
    const int lm = lane & 15, lk = (lane >> 4) * 8;
    const int sr = tid >> 2, sc = (tid & 3) * 8;
    f32x4 acc[2] = {};
    for (int it = 0; it < 8; ++it) {
        int kk = ks * 256 + it * 32;
        *(uint4*)&Ab[sr][sc] = *(const uint4*)(Abf + (size_t)(m0 + sr) * NNODE + kk + sc);
        if (tid < 128) {
            int row = tid >> 2, c = (tid & 3) * 8;
            *(uint4*)&Bb[row][c] = *(const uint4*)(Gt + (size_t)row * NNODE + kk + c);
        }
        __syncthreads();
        short8 a  = *(const short8*)&Ab[wave * 16 + lm][lk];
        short8 b0 = *(const short8*)&Bb[lm][lk];
        short8 b1 = *(const short8*)&Bb[16 + lm][lk];
        acc[0] = __builtin_amdgcn_mfma_f32_16x16x32_bf16(a, b0, acc[0], 0, 0, 0);
        acc[1] = __builtin_amdgcn_mfma_f32_16x16x32_bf16(a, b1, acc[1], 0, 0, 0);
        __syncthreads();
    }
    float* outp = Mp + (size_t)ks * 65536;
    #pragma unroll
    for (int ni = 0; ni < 2; ++ni)
        #pragma unroll
        for (int r = 0; r < 4; ++r) {
            int row = m0 + wave * 16 + (lane >> 4) * 4 + r;
            int col = ni * 16 + lm;
            outp[(size_t)row * H2 + col] = acc[ni][r];
        }
}

// ---------------- T5: reduce Mp; mu/logvar; Z; P', Q, and WP/WQ ------------------
__global__ __launch_bounds__(256) void t5_z(const float* __restrict__ Mp,
                                            const float* __restrict__ bmu,
                                            const float* __restrict__ blv,
                                            const float* __restrict__ eps,
                                            const float* __restrict__ Wd1,
                                            const float* __restrict__ bd1,
                                            const float* __restrict__ Wd2,
                                            float* __restrict__ out_mu,
                                            float* __restrict__ out_lv,
                                            float* __restrict__ Pp,
                                            float* __restrict__ Qq,
                                            float* __restrict__ WP,
                                            float* __restrict__ WQ) {
    __shared__ float Zs[16][16];
    __shared__ float Psh[16][32];
    __shared__ float Qsh[16][32];
    const int tid = threadIdx.x;
    const int n0 = blockIdx.x * 16;
    {
        int nl = tid >> 4, l = tid & 15;
        int n = n0 + nl;
        float m = bmu[l], lv = blv[l];
        #pragma unroll
        for (int s = 0; s < 8; ++s) {
            m  += Mp[(size_t)s * 65536 + (size_t)n * H2 + l];
            lv += Mp[(size_t)s * 65536 + (size_t)n * H2 + 16 + l];
        }
        out_mu[(size_t)n * LLAT + l] = m;
        out_lv[(size_t)n * LLAT + l] = lv;
        Zs[nl][l] = m + eps[(size_t)n * LLAT + l] * __expf(0.5f * lv);
    }
    __syncthreads();
    #pragma unroll
    for (int p = 0; p < 2; ++p) {
        int idx = tid + p * 256;            // 0..511
        int nl = idx >> 5, o = idx & 31;
        int n = n0 + nl;
        float ap = bd1[o], aq = 0.f;
        #pragma unroll
        for (int l = 0; l < 16; ++l) {
            float z = Zs[nl][l];
            ap = fmaf(z, Wd1[o * H2 + l],      ap);
            aq = fmaf(z, Wd1[o * H2 + 16 + l], aq);
        }
        Pp[(size_t)n * H2 + o] = ap;
        Qq[(size_t)n * H2 + o] = aq;
        Psh[nl][o] = ap;
        Qsh[nl][o] = aq;
    }
    __syncthreads();
    if (tid < 32) {
        int nl = tid & 15, sel = tid >> 4;
        float a = 0.f;
        if (sel == 0) {
            #pragma unroll
            for (int o = 0; o < 32; ++o) a = fmaf(Wd2[o], Psh[nl][o], a);
            WP[n0 + nl] = a;
        } else {
            #pragma unroll
            for (int o = 0; o < 32; ++o) a = fmaf(Wd2[o], Qsh[nl][o], a);
            WQ[n0 + nl] = a;
        }
    }
}

// ---------------- T6: decoder via leaky(x)=0.505x+0.495|x| decomposition ---------
__global__ __launch_bounds__(256) void t6_dec(const float* __restrict__ Pp,
                                              const float* __restrict__ Qq,
                                              const float* __restrict__ WP,
                                              const float* __restrict__ WQ,
                                              const float* __restrict__ Wd2,
                                              const float* __restrict__ bd2,
                                              float* __restrict__ Apred) {
    __shared__ float Qt[32][68];   // transposed Q tile, padded
    __shared__ float Ws2[32];
    __shared__ float WQs[64];
    const int tid = threadIdx.x;
    const int j0 = blockIdx.x * 64, i0 = blockIdx.y * 16;
    #pragma unroll
    for (int s = 0; s < 8; ++s) {
        int idx = tid + s * 256;            // 0..2047
        int j = idx >> 5, o = idx & 31;
        Qt[o][j] = Qq[(size_t)(j0 + j) * H2 + o];
    }
    if (tid < 32) Ws2[tid] = Wd2[tid];
    if (tid >= 64 && tid < 128) WQs[tid - 64] = WQ[j0 + tid - 64];
    const int i = i0 + (tid >> 4);
    const int jq = tid & 15;
    float p[32];
    const float4* P4 = (const float4*)(Pp + (size_t)i * H2);
    #pragma unroll
    for (int c = 0; c < 8; ++c) {
        float4 v = P4[c];
        p[c * 4] = v.x; p[c * 4 + 1] = v.y; p[c * 4 + 2] = v.z; p[c * 4 + 3] = v.w;
    }
    const float WPi = WP[i];
    __syncthreads();
    f32x4 acc = {0.f, 0.f, 0.f, 0.f};   // sum_o w*|P+Q|
    #pragma unroll
    for (int o = 0; o < 32; ++o) {
        float4 q = *(const float4*)&Qt[o][jq * 4];
        float w = Ws2[o], po = p[o];
        acc[0] = fmaf(w, fabsf(po + q.x), acc[0]);
        acc[1] = fmaf(w, fabsf(po + q.y), acc[1]);
        acc[2] = fmaf(w, fabsf(po + q.z), acc[2]);
        acc[3] = fmaf(w, fabsf(po + q.w), acc[3]);
    }
    float4 wq = *(const float4*)&WQs[jq * 4];
    const float base = fmaf(0.505f, WPi, bd2[0]);
    float4 r;
    float l0 = fmaf(0.505f, wq.x, fmaf(0.495f, acc[0], base));
    float l1 = fmaf(0.505f, wq.y, fmaf(0.495f, acc[1], base));
    float l2 = fmaf(0.505f, wq.z, fmaf(0.495f, acc[2], base));
    float l3 = fmaf(0.505f, wq.w, fmaf(0.495f, acc[3], base));
    r.x = 1.f / (1.f + __expf(-l0));
    r.y = 1.f / (1.f + __expf(-l1));
    r.z = 1.f / (1.f + __expf(-l2));
    r.w = 1.f / (1.f + __expf(-l3));
    *(float4*)(Apred + (size_t)i * NNODE + j0 + jq * 4) = r;
}

extern "C" void kernel_launch(void* const* d_in, const int* in_sizes, int n_in,
                              void* d_out, int out_size, void* d_ws, size_t ws_size,
                              hipStream_t stream) {
    const float* A   = (const float*)d_in[0];
    const float* X   = (const float*)d_in[1];
    const float* eps = (const float*)d_in[2];
    const float* W1  = (const float*)d_in[3];
    const float* b1  = (const float*)d_in[4];
    const float* Wmu = (const float*)d_in[5];
    const float* bmu = (const float*)d_in[6];
    const float* Wlv = (const float*)d_in[7];
    const float* blv = (const float*)d_in[8];
    const float* Wd1 = (const float*)d_in[9];
    const float* bd1 = (const float*)d_in[10];
    const float* Wd2 = (const float*)d_in[11];
    const float* bd2 = (const float*)d_in[12];
    float* out = (float*)d_out;
    char* ws = (char*)d_ws;

    // workspace carve (~18.8 MB), all buffers fully overwritten each call
    unsigned short* Abf  = (unsigned short*)(ws);               //  8,388,608
    unsigned short* Xbf  = (unsigned short*)(ws + 8388608);     //  2,097,152
    unsigned short* W1bf = (unsigned short*)(ws + 10485760);    //    262,144
    unsigned short* XWt  = (unsigned short*)(ws + 10747904);    //  1,048,576
    unsigned short* Hp16 = (unsigned short*)(ws + 11796480);    //  4,194,304 (4 x 1MB)
    unsigned short* Gt   = (unsigned short*)(ws + 15990784);    //    131,072
    float*          Mp   = (float*)(ws + 16121856);             //  2,097,152 (8 x 256KB)
    float*          Pp   = (float*)(ws + 18219008);             //    262,144
    float*          Qq   = (float*)(ws + 18481152);             //    262,144
    float*          WP   = (float*)(ws + 18743296);             //      8,192
    float*          WQ   = (float*)(ws + 18751488);             //      8,192

    float* out_mu = out + (size_t)NNODE * NNODE;
    float* out_lv = out_mu + NNODE * LLAT;

    t0_cvt <<<2048,            256, 0, stream>>>(A, X, W1, Abf, Xbf, W1bf);
    t1_full<<<dim3(64, 8),     256, 0, stream>>>(W1bf, Xbf, XWt);
    t2_mfma<<<dim3(32, 4, 4),  256, 0, stream>>>(Abf, XWt, Hp16);
    t3h    <<<256,             256, 0, stream>>>(Hp16, b1, Wmu, Wlv, Gt);
    t4_mfma<<<dim3(32, 8),     256, 0, stream>>>(Abf, Gt, Mp);
    t5_z   <<<128,             256, 0, stream>>>(Mp, bmu, blv, eps, Wd1, bd1, Wd2,
                                                 out_mu, out_lv, Pp, Qq, WP, WQ);
    t6_dec <<<dim3(32, 128),   256, 0, stream>>>(Pp, Qq, WP, WQ, Wd2, bd2, out);
}